// Round 9
// baseline (1360.040 us; speedup 1.0000x reference)
//
#include <hip/hip_runtime.h>
#include <hip/hip_bf16.h>
#include <hip/hip_fp16.h>

#define LN_F 128

typedef __attribute__((ext_vector_type(8))) __bf16 bf16x8;
typedef __attribute__((ext_vector_type(4))) float f32x4;
typedef __attribute__((ext_vector_type(2))) _Float16 half2_t;

__device__ __forceinline__ unsigned short f2bf(float f) {
    unsigned u = __float_as_uint(f);
    u = u + 0x7FFFu + ((u >> 16) & 1u);   // RNE
    return (unsigned short)(u >> 16);
}
// deg-7 odd Taylor (f32, cold paths)
__device__ __forceinline__ float tanh_polyc(float x) {
    x = fminf(1.2f, fmaxf(-1.2f, x));
    float t = x * x;
    float p = fmaf(t, -0.05396825397f, 0.13333333333f);
    p = fmaf(t, p, -0.33333333333f);
    p = fmaf(t, p, 1.0f);
    return x * p;
}
__device__ __forceinline__ float bflo(unsigned u) { return __uint_as_float(u << 16); }
__device__ __forceinline__ float bfhi(unsigned u) { return __uint_as_float(u & 0xffff0000u); }

// f32 -> e5m2 byte (e5m2 == top byte of f16; double-RNE)
__device__ __forceinline__ unsigned f2e5(float x) {
    unsigned short u = __half_as_ushort(__float2half(x));
    u = (unsigned short)(u + 0x7F + ((u >> 8) & 1));
    return (unsigned)(u >> 8) & 0xFFu;
}
__device__ __forceinline__ half2_t u2h2(unsigned w) {
    union { unsigned u; half2_t h; } c; c.u = w; return c.h;
}
__device__ __forceinline__ unsigned h2u(half2_t h) {
    union { half2_t h; unsigned u; } c; c.h = h; return c.u;
}
// packed deg-5 odd Taylor tanh on half2
__device__ __forceinline__ half2_t tanh_pk(half2_t x) {
    const half2_t c2 = {(_Float16)(2.0f / 15.0f), (_Float16)(2.0f / 15.0f)};
    const half2_t c1 = {(_Float16)(-1.0f / 3.0f), (_Float16)(-1.0f / 3.0f)};
    const half2_t one = {(_Float16)1.0f, (_Float16)1.0f};
    half2_t t = x * x;
    half2_t p = t * c2 + c1;
    p = t * p + one;
    return x * p;
}

// ---------------- grid barrier (all blocks must be co-resident) ----------------
// syncv: 64 counters at stride 16 ints + gen flag at [1024]; zeroed before launch.
__device__ __forceinline__ void gbar(int* syncv, int phase, int nb) {
    __threadfence();
    __syncthreads();
    if (threadIdx.x == 0)
        __hip_atomic_fetch_add(&syncv[(blockIdx.x & 63) << 4], 1,
                               __ATOMIC_RELEASE, __HIP_MEMORY_SCOPE_AGENT);
    if (blockIdx.x == 0) {
        if (threadIdx.x < 64) {
            int q = nb >> 6, r = nb & 63;
            int per = q + ((int)threadIdx.x < r ? 1 : 0);
            while (__hip_atomic_load(&syncv[threadIdx.x << 4],
                                     __ATOMIC_ACQUIRE, __HIP_MEMORY_SCOPE_AGENT) < per * phase)
                __builtin_amdgcn_s_sleep(4);
        }
        __syncthreads();
        if (threadIdx.x == 0)
            __hip_atomic_store(&syncv[1024], phase,
                               __ATOMIC_RELEASE, __HIP_MEMORY_SCOPE_AGENT);
    } else {
        if (threadIdx.x == 0) {
            while (__hip_atomic_load(&syncv[1024],
                                     __ATOMIC_ACQUIRE, __HIP_MEMORY_SCOPE_AGENT) < phase)
                __builtin_amdgcn_s_sleep(4);
        }
    }
    __syncthreads();
    __threadfence();
}

// ---------------- conversions (emb/Wc/rou) + fused histogram ----------------
__global__ void k_conv(const float* __restrict__ emb, const float* __restrict__ xiw,
                       const float* __restrict__ rw, const int* __restrict__ Xe,
                       unsigned short* __restrict__ embb, unsigned short* __restrict__ WcT,
                       unsigned short* __restrict__ rouT, int* __restrict__ cnt,
                       int V, int E) {
    int t = blockIdx.x * blockDim.x + threadIdx.x;
    int n_emb = V * 16;
    if (t < n_emb) {
        const float4* s = (const float4*)emb;
        float4 a = s[t * 2], b = s[t * 2 + 1];
        uint4 o;
        o.x = (unsigned)f2bf(a.x) | ((unsigned)f2bf(a.y) << 16);
        o.y = (unsigned)f2bf(a.z) | ((unsigned)f2bf(a.w) << 16);
        o.z = (unsigned)f2bf(b.x) | ((unsigned)f2bf(b.y) << 16);
        o.w = (unsigned)f2bf(b.z) | ((unsigned)f2bf(b.w) << 16);
        ((uint4*)embb)[t] = o;
    } else if (t < n_emb + 512 * 16) {
        int t2 = t - n_emb;
        int cp = t2 >> 4, g = t2 & 15;
        unsigned short u[8];
#pragma unroll
        for (int j = 0; j < 8; ++j) {
            int k = g * 8 + j;
            float w = (cp < 256) ? xiw[k * 256 + cp] : xiw[(128 + k) * 256 + (cp - 256)];
            u[j] = f2bf(w);
        }
        uint4 o;
        o.x = (unsigned)u[0] | ((unsigned)u[1] << 16);
        o.y = (unsigned)u[2] | ((unsigned)u[3] << 16);
        o.z = (unsigned)u[4] | ((unsigned)u[5] << 16);
        o.w = (unsigned)u[6] | ((unsigned)u[7] << 16);
        ((uint4*)WcT)[cp * 16 + (g ^ (cp & 7))] = o;
    } else if (t < n_emb + 512 * 16 + 256) {
        int t2 = t - n_emb - 512 * 16;
        int c = t2 >> 4, g = t2 & 15;
        unsigned short u[8];
#pragma unroll
        for (int j = 0; j < 8; ++j) u[j] = f2bf(rw[(g * 8 + j) * 16 + c]);
        uint4 o;
        o.x = (unsigned)u[0] | ((unsigned)u[1] << 16);
        o.y = (unsigned)u[2] | ((unsigned)u[3] << 16);
        o.z = (unsigned)u[4] | ((unsigned)u[5] << 16);
        o.w = (unsigned)u[6] | ((unsigned)u[7] << 16);
        ((uint4*)rouT)[c * 16 + (g ^ (c & 7))] = o;
    }
    if (t < E) atomicAdd(&cnt[Xe[t]], 1);   // fused histogram
}

// ---------------- fused two-level exclusive scan (NB blocks, NB<=256) ----------------
__global__ __launch_bounds__(256) void k_scanf(const int* __restrict__ cnt,
                                               int* __restrict__ rp,
                                               int* __restrict__ bsum,
                                               int* __restrict__ boff,
                                               int* __restrict__ syncv, int V, int NB) {
    __shared__ int ls[256];
    int b = blockIdx.x, t = threadIdx.x;
    int i = b * 256 + t;
    int val = (i < V) ? cnt[i] : 0;
    ls[t] = val;
    __syncthreads();
    for (int off = 1; off < 256; off <<= 1) {
        int x = (t >= off) ? ls[t - off] : 0;
        __syncthreads();
        ls[t] += x;
        __syncthreads();
    }
    if (i < V) rp[i] = ls[t] - val;
    if (t == 255) bsum[b] = ls[255];

    gbar(syncv, 1, NB);

    if (b == 0) {
        int v2 = (t < NB) ? bsum[t] : 0;
        ls[t] = v2;
        __syncthreads();
        for (int off = 1; off < 256; off <<= 1) {
            int x = (t >= off) ? ls[t - off] : 0;
            __syncthreads();
            ls[t] += x;
            __syncthreads();
        }
        if (t < NB) boff[t] = ls[t] - v2;
        if (t == 255) rp[V] = ls[255];
    }

    gbar(syncv, 2, NB);

    if (i < V) rp[i] += boff[b];
}

// ---------------- permute (counting-sort placement) + fused pad fill ----------------
__global__ void k_permute(const int* __restrict__ Xn, const int* __restrict__ Xe,
                          const int* __restrict__ dg, const int* __restrict__ rp,
                          int* __restrict__ c2, int2* __restrict__ edata,
                          int* __restrict__ edst, int n, int Epad) {
    int e = blockIdx.x * blockDim.x + threadIdx.x;
    if (e < n) {
        int nb = Xe[e];
        int pos = rp[nb] + atomicAdd(&c2[nb], 1);
        edata[pos] = make_int2(Xn[e], __float_as_int(0.05625f / (float)dg[e]));
        edst[pos] = nb;
    } else if (e < Epad) {
        edata[e] = make_int2(0, 0);
        edst[e] = 0;
    }
}

// ---------------- U tables (e5m2) + bnode(f32) ----------------
__global__ __launch_bounds__(512) void k_U(
    const unsigned short* __restrict__ embb, const uint4* __restrict__ WcT,
    const uint4* __restrict__ rouT, const float* __restrict__ xib,
    const float* __restrict__ roub,
    unsigned* __restrict__ U8, unsigned* __restrict__ U28,
    float* __restrict__ bnode, int V) {
    __shared__ uint4 sB[2048];
    __shared__ uint4 sR[256];
    const int half = blockIdx.y;
    for (int i = threadIdx.x; i < 2048; i += 512) sB[i] = WcT[half * 2048 + i];
    if (half == 0 && threadIdx.x < 256) sR[threadIdx.x] = rouT[threadIdx.x];
    __syncthreads();

    const int wave = threadIdx.x >> 6, lane = threadIdx.x & 63;
    const int j = lane & 15, kg = lane >> 4;
    const int wbase = blockIdx.x * 512 + wave * 64;

    int nv[4];
#pragma unroll
    for (int g = 0; g < 4; ++g) nv[g] = min(wbase + g * 16 + j, V - 1);

    f32x4 acc[8][4] = {};
    f32x4 accb[4] = {};
#pragma unroll
    for (int kc = 0; kc < 4; ++kc) {
        bf16x8 bf[4];
#pragma unroll
        for (int g = 0; g < 4; ++g)
            bf[g] = *(const bf16x8*)(embb + (size_t)nv[g] * 128 + kc * 32 + kg * 8);
        int swz = (kc * 4 + kg) ^ (j & 7);
#pragma unroll
        for (int ct = 0; ct < 8; ++ct) {
            bf16x8 afr = ((const bf16x8*)sB)[(ct * 16 + j) * 16 + swz];
#pragma unroll
            for (int g = 0; g < 4; ++g)
                acc[ct][g] = __builtin_amdgcn_mfma_f32_16x16x32_bf16(afr, bf[g], acc[ct][g], 0, 0, 0);
        }
        if (half == 0) {
            bf16x8 rfr = ((const bf16x8*)sR)[j * 16 + swz];
#pragma unroll
            for (int g = 0; g < 4; ++g)
                accb[g] = __builtin_amdgcn_mfma_f32_16x16x32_bf16(rfr, bf[g], accb[g], 0, 0, 0);
        }
    }

#pragma unroll
    for (int ct = 0; ct < 8; ++ct) {
        int c0 = half * 128 + ct * 16 + kg * 4;     // 0..511
        float4 bias = (half < 2) ? ((const float4*)xib)[c0 >> 2]
                                 : make_float4(0.f, 0.f, 0.f, 0.f);
#pragma unroll
        for (int g = 0; g < 4; ++g) {
            int node = wbase + g * 16 + j;
            if (node < V) {
                const f32x4 a = acc[ct][g];
                float v0 = a[0] + bias.x, v1 = a[1] + bias.y;
                float v2 = a[2] + bias.z, v3 = a[3] + bias.w;
                unsigned pk = f2e5(v0) | (f2e5(v1) << 8) | (f2e5(v2) << 16) | (f2e5(v3) << 24);
                if (half < 2) U8[node * 64 + (c0 >> 2)] = pk;
                else          U28[node * 64 + ((c0 - 256) >> 2)] = pk;
            }
        }
    }
    if (half == 0) {
        float4 rb4 = ((const float4*)roub)[kg];
#pragma unroll
        for (int g = 0; g < 4; ++g) {
            int node = wbase + g * 16 + j;
            if (node < V) {
                float4 bo;
                bo.x = tanh_polyc(accb[g][0] + rb4.x);
                bo.y = tanh_polyc(accb[g][1] + rb4.y);
                bo.z = tanh_polyc(accb[g][2] + rb4.z);
                bo.w = tanh_polyc(accb[g][3] + rb4.w);
                *(float4*)(bnode + (size_t)node * 16 + kg * 4) = bo;
            }
        }
    }
}

// ---------------- per-task bodies for the mega kernel ----------------
__device__ __forceinline__ void b1e_task(
    int task, const float* __restrict__ bnode, const int2* __restrict__ edata,
    const int* __restrict__ edst, float* __restrict__ B1, int E, int Epad, int lane) {
    int wbase = task << 6;
    int g = lane >> 4, s = lane & 15, lbase = g * 16;
    int sbase = wbase + lbase;
    int em = wbase + lane;
    int d_own = edst[em];
    int d_nxt = edst[min(em + 1, Epad - 1)];
    unsigned long long flags = __ballot(d_own != d_nxt);
    int cur = edst[sbase];
    float acc = 0.f;
#pragma unroll 4
    for (int j = 0; j < 16; ++j) {
        int p = sbase + j;
        int u = edata[p].x;
        float v = bnode[(size_t)u * 16 + s];
        acc += (p < E) ? v : 0.f;
        bool flush = ((flags >> (lbase + j)) & 1ull) || (j == 15);
        if (flush) {
            atomicAdd(&B1[(size_t)cur * 16 + s], acc);
            acc = 0.f;
            if (j < 15) cur = edst[p + 1];
        }
    }
}

__device__ __forceinline__ void prop_task(
    int task, const unsigned* __restrict__ U8, const unsigned* __restrict__ U28,
    const int2* __restrict__ edata, const int* __restrict__ edst,
    const unsigned* __restrict__ Hf, float* __restrict__ sn, int Epad, int lane) {
    int wbase = task << 6;
    int g = lane >> 4, s = lane & 15, lbase = g * 16;
    int sbase = wbase + lbase;
    int em = wbase + lane;
    int d_own = edst[em];
    int d_nxt = edst[min(em + 1, Epad - 1)];
    unsigned long long flags = __ballot(d_own != d_nxt);
    int cur = edst[sbase];
    half2_t u2h[8];
    {
        uint4 r = ((const uint4*)U28)[cur * 16 + s];
        unsigned wr[4] = {r.x, r.y, r.z, r.w};
#pragma unroll
        for (int q = 0; q < 4; ++q) {
            u2h[2 * q]     = u2h2(__builtin_amdgcn_perm(wr[q], 0u, 0x05000400u));
            u2h[2 * q + 1] = u2h2(__builtin_amdgcn_perm(wr[q], 0u, 0x07000600u));
        }
    }
    float acc = 0.f;
#pragma unroll 2
    for (int j = 0; j < 16; ++j) {
        int p = sbase + j;
        int2 ed = edata[p];
        int u = ed.x;
        float sc = __int_as_float(ed.y);
        uint4 q1 = ((const uint4*)U8)[u * 16 + s];
        unsigned h2 = Hf[u * 8 + (s & 7)];
        unsigned wq[4] = {q1.x, q1.y, q1.z, q1.w};
        float sum = 0.f;
#pragma unroll
        for (int q = 0; q < 4; ++q) {
            half2_t x0 = u2h2(__builtin_amdgcn_perm(wq[q], 0u, 0x05000400u)) + u2h[2 * q];
            half2_t x1 = u2h2(__builtin_amdgcn_perm(wq[q], 0u, 0x07000600u)) + u2h[2 * q + 1];
            half2_t r0 = tanh_pk(x0);
            half2_t r1 = tanh_pk(x1);
            unsigned hm0 = __shfl(h2, lbase + 2 * q, 64);
            unsigned hm1 = __shfl(h2, lbase + 2 * q + 1, 64);
            sum = __builtin_amdgcn_fdot2(r0, u2h2(hm0), sum, false);
            sum = __builtin_amdgcn_fdot2(r1, u2h2(hm1), sum, false);
        }
        acc = fmaf(sc, sum, acc);
        bool flush = ((flags >> (lbase + j)) & 1ull) || (j == 15);
        if (flush) {
            atomicAdd(&sn[(size_t)cur * 16 + s], acc);
            acc = 0.f;
            if (j < 15) {
                cur = edst[p + 1];
                uint4 r = ((const uint4*)U28)[cur * 16 + s];
                unsigned wr[4] = {r.x, r.y, r.z, r.w};
#pragma unroll
                for (int q = 0; q < 4; ++q) {
                    u2h[2 * q]     = u2h2(__builtin_amdgcn_perm(wr[q], 0u, 0x05000400u));
                    u2h[2 * q + 1] = u2h2(__builtin_amdgcn_perm(wr[q], 0u, 0x07000600u));
                }
            }
        }
    }
}

// ---------------- persistent mega kernel: B1e -> prep -> prop2 -> prep -> prop3 -> final ----------------
// 1024 blocks x 256 thr; launch_bounds(256,4) => <=128 VGPR => 4 blocks/CU => all co-resident.
__global__ __launch_bounds__(256, 4) void k_mega(
    const float* __restrict__ bnode, const int2* __restrict__ edata,
    const int* __restrict__ edst,
    const unsigned* __restrict__ U8, const unsigned* __restrict__ U28,
    float* __restrict__ B1, float* __restrict__ stB, float* __restrict__ stA,
    unsigned* __restrict__ Hf,
    const unsigned short* __restrict__ embb,
    const float* __restrict__ lw, const float* __restrict__ lb,
    float* __restrict__ out,
    int* __restrict__ syncv, int V, int E, int Epad) {
    const int nb = gridDim.x;
    const int nthreads = nb << 8;
    const int nwaves = nthreads >> 6;
    const int tid0 = (blockIdx.x << 8) + threadIdx.x;
    const int wid0 = tid0 >> 6;
    const int lane = threadIdx.x & 63;
    const int ntask = Epad >> 6;
    const int n2 = V * 8;

    // phase 1: B1 (pre-zeroed) += segment-sum of bnode[src]
    for (int task = wid0; task < ntask; task += nwaves)
        b1e_task(task, bnode, edata, edst, B1, E, Epad, lane);
    gbar(syncv, 1, nb);

    // phase 2: Hf = f16(B1); zero delta buffers
    for (int i = tid0; i < n2; i += nthreads) {
        float2 f = ((const float2*)B1)[i];
        half2_t h = {(_Float16)f.x, (_Float16)f.y};
        Hf[i] = h2u(h);
        ((float2*)stB)[i] = make_float2(0.f, 0.f);
        ((float2*)stA)[i] = make_float2(0.f, 0.f);
    }
    gbar(syncv, 2, nb);

    // phase 3: stB += scatter(A @ h1)
    for (int task = wid0; task < ntask; task += nwaves)
        prop_task(task, U8, U28, edata, edst, Hf, stB, Epad, lane);
    gbar(syncv, 3, nb);

    // phase 4: Hf = f16(B1 + stB)
    for (int i = tid0; i < n2; i += nthreads) {
        float2 f = ((const float2*)B1)[i];
        float2 d = ((const float2*)stB)[i];
        half2_t h = {(_Float16)(f.x + d.x), (_Float16)(f.y + d.y)};
        Hf[i] = h2u(h);
    }
    gbar(syncv, 4, nb);

    // phase 5: stA += scatter(A @ h2)
    for (int task = wid0; task < ntask; task += nwaves)
        prop_task(task, U8, U28, edata, edst, Hf, stA, Epad, lane);
    gbar(syncv, 5, nb);

    // phase 6: final softmax([emb, B1+stA] @ lin_w + lin_b)
    __shared__ float sw[435];
    for (int i = threadIdx.x; i < 435; i += 256) sw[i] = (i < 432) ? lw[i] : lb[i - 432];
    __syncthreads();
    const int ntot = V * 16;
    for (int t = tid0; t < ntot; t += nthreads) {
        int v = t >> 4, j = t & 15;
        const uint4 q = *(const uint4*)(embb + (size_t)v * 128 + j * 8);
        unsigned uu[4] = {q.x, q.y, q.z, q.w};
        float a0 = 0.f, a1 = 0.f, a2 = 0.f;
#pragma unroll
        for (int m = 0; m < 4; ++m) {
            int i = j * 8 + 2 * m;
            float x0 = bflo(uu[m]), x1 = bfhi(uu[m]);
            a0 += x0 * sw[i * 3] + x1 * sw[(i + 1) * 3];
            a1 += x0 * sw[i * 3 + 1] + x1 * sw[(i + 1) * 3 + 1];
            a2 += x0 * sw[i * 3 + 2] + x1 * sw[(i + 1) * 3 + 2];
        }
        float xs = B1[(size_t)v * 16 + j] + stA[(size_t)v * 16 + j];
        a0 += xs * sw[(128 + j) * 3]; a1 += xs * sw[(128 + j) * 3 + 1]; a2 += xs * sw[(128 + j) * 3 + 2];
#pragma unroll
        for (int m = 1; m < 16; m <<= 1) {
            a0 += __shfl_xor(a0, m, 64);
            a1 += __shfl_xor(a1, m, 64);
            a2 += __shfl_xor(a2, m, 64);
        }
        if (j == 0) {
            a0 += sw[432]; a1 += sw[433]; a2 += sw[434];
            float mx = fmaxf(a0, fmaxf(a1, a2));
            float e0 = __expf(a0 - mx), e1 = __expf(a1 - mx), e2 = __expf(a2 - mx);
            float inv = 1.f / (e0 + e1 + e2);
            out[(size_t)v * 3 + 0] = e0 * inv;
            out[(size_t)v * 3 + 1] = e1 * inv;
            out[(size_t)v * 3 + 2] = e2 * inv;
        }
    }
}

extern "C" void kernel_launch(void* const* d_in, const int* in_sizes, int n_in,
                              void* d_out, int out_size, void* d_ws, size_t ws_size,
                              hipStream_t stream) {
    const int*   Xn  = (const int*)d_in[0];
    const int*   Xe  = (const int*)d_in[1];
    const int*   dg  = (const int*)d_in[2];
    const float* emb = (const float*)d_in[3];
    const float* xiw = (const float*)d_in[4];
    const float* xib = (const float*)d_in[5];
    const float* rw  = (const float*)d_in[6];
    const float* rb  = (const float*)d_in[7];
    const float* lw  = (const float*)d_in[8];
    const float* lb  = (const float*)d_in[9];
    float* out = (float*)d_out;
    const int E = in_sizes[0];
    const int V = in_sizes[3] / LN_F;
    const int NB = (V + 255) / 256;            // <= 256 required (V <= 65536)
    const int Epad = (E + 63) & ~63;

    char* p = (char*)d_ws;
    auto carve = [&](size_t bytes) {
        char* q = p; p += (bytes + 255) & ~(size_t)255; return q;
    };
    // zero-region: cnt, c2, syncA, syncB, B1 (single memset covers all)
    int*   cnt   = (int*)carve((size_t)V * 4);
    int*   c2    = (int*)carve((size_t)V * 4);
    int*   syncA = (int*)carve(1040 * 4);
    int*   syncB = (int*)carve(1040 * 4);
    float* B1    = (float*)carve((size_t)V * 16 * 4);
    size_t zero_bytes = (size_t)(p - (char*)cnt);
    // rest
    unsigned short* embb = (unsigned short*)carve((size_t)V * 128 * 2);
    unsigned* U8    = (unsigned*)carve((size_t)V * 256);
    unsigned* U28   = (unsigned*)carve((size_t)V * 256);
    uint4* WcT   = (uint4*)carve(512 * 16 * 16);
    uint4* rouT  = (uint4*)carve(4096);
    float* bnode = (float*)carve((size_t)V * 16 * 4);
    float* stB   = (float*)carve((size_t)V * 16 * 4);
    float* stA   = (float*)carve((size_t)V * 16 * 4);
    unsigned* Hf = (unsigned*)carve((size_t)V * 16 * 2);
    int*   rp    = (int*)carve((size_t)(V + 1) * 4);
    int*   bsum  = (int*)carve(256 * 4);
    int*   boff  = (int*)carve(256 * 4);
    int2*  edata = (int2*)carve((size_t)Epad * 8);
    int*   edst  = (int*)carve((size_t)Epad * 4);

    // 1: zero cnt/c2/sync/B1
    hipMemsetAsync(cnt, 0, zero_bytes, stream);

    // 2: conversions + histogram
    {
        int nconv = V * 16 + 512 * 16 + 256;
        int ntot = nconv > E ? nconv : E;
        k_conv<<<(ntot + 255) / 256, 256, 0, stream>>>(
            emb, xiw, rw, Xe, embb, (unsigned short*)WcT, (unsigned short*)rouT, cnt, V, E);
    }

    // 3: fused two-level scan
    k_scanf<<<NB, 256, 0, stream>>>(cnt, rp, bsum, boff, syncA, V, NB);

    // 4: permute + pad fill
    k_permute<<<(E + 255) / 256, 256, 0, stream>>>(Xn, Xe, dg, rp, c2, edata, edst, E, Epad);

    // 5: U tables + bnode
    {
        dim3 g((V + 511) / 512, 4);
        k_U<<<g, 512, 0, stream>>>(embb, WcT, rouT, xib, rb, U8, U28, bnode, V);
    }

    // 6: persistent fused pipeline
    k_mega<<<1024, 256, 0, stream>>>(bnode, edata, edst, U8, U28,
                                     B1, stB, stA, Hf, embb, lw, lb, out,
                                     syncB, V, E, Epad);
}

// Round 10
// 184.649 us; speedup vs baseline: 7.3656x; 7.3656x over previous
//
#include <hip/hip_runtime.h>
#include <hip/hip_bf16.h>
#include <hip/hip_fp16.h>

#define LN_F 128

typedef __attribute__((ext_vector_type(8))) __bf16 bf16x8;
typedef __attribute__((ext_vector_type(4))) float f32x4;
typedef __attribute__((ext_vector_type(2))) _Float16 half2_t;

__device__ __forceinline__ unsigned short f2bf(float f) {
    unsigned u = __float_as_uint(f);
    u = u + 0x7FFFu + ((u >> 16) & 1u);   // RNE
    return (unsigned short)(u >> 16);
}
// deg-7 odd Taylor (f32, cold paths)
__device__ __forceinline__ float tanh_polyc(float x) {
    x = fminf(1.2f, fmaxf(-1.2f, x));
    float t = x * x;
    float p = fmaf(t, -0.05396825397f, 0.13333333333f);
    p = fmaf(t, p, -0.33333333333f);
    p = fmaf(t, p, 1.0f);
    return x * p;
}
__device__ __forceinline__ float bflo(unsigned u) { return __uint_as_float(u << 16); }
__device__ __forceinline__ float bfhi(unsigned u) { return __uint_as_float(u & 0xffff0000u); }

// f32 -> e5m2 byte (e5m2 == top byte of f16; double-RNE)
__device__ __forceinline__ unsigned f2e5(float x) {
    unsigned short u = __half_as_ushort(__float2half(x));
    u = (unsigned short)(u + 0x7F + ((u >> 8) & 1));
    return (unsigned)(u >> 8) & 0xFFu;
}
__device__ __forceinline__ half2_t u2h2(unsigned w) {
    union { unsigned u; half2_t h; } c; c.u = w; return c.h;
}
__device__ __forceinline__ unsigned h2u(half2_t h) {
    union { half2_t h; unsigned u; } c; c.h = h; return c.u;
}
// packed deg-5 odd Taylor tanh on half2
__device__ __forceinline__ half2_t tanh_pk(half2_t x) {
    const half2_t c2 = {(_Float16)(2.0f / 15.0f), (_Float16)(2.0f / 15.0f)};
    const half2_t c1 = {(_Float16)(-1.0f / 3.0f), (_Float16)(-1.0f / 3.0f)};
    const half2_t one = {(_Float16)1.0f, (_Float16)1.0f};
    half2_t t = x * x;
    half2_t p = t * c2 + c1;
    p = t * p + one;
    return x * p;
}

// ---------------- conversions (emb/Wc/rou) + fused histogram + B1 zero ----------------
__global__ void k_conv(const float* __restrict__ emb, const float* __restrict__ xiw,
                       const float* __restrict__ rw, const int* __restrict__ Xe,
                       unsigned short* __restrict__ embb, unsigned short* __restrict__ WcT,
                       unsigned short* __restrict__ rouT, int* __restrict__ cnt,
                       float* __restrict__ B1, int V, int E) {
    int t = blockIdx.x * blockDim.x + threadIdx.x;
    int n_emb = V * 16;
    if (t < n_emb) {
        const float4* s = (const float4*)emb;
        float4 a = s[t * 2], b = s[t * 2 + 1];
        uint4 o;
        o.x = (unsigned)f2bf(a.x) | ((unsigned)f2bf(a.y) << 16);
        o.y = (unsigned)f2bf(a.z) | ((unsigned)f2bf(a.w) << 16);
        o.z = (unsigned)f2bf(b.x) | ((unsigned)f2bf(b.y) << 16);
        o.w = (unsigned)f2bf(b.z) | ((unsigned)f2bf(b.w) << 16);
        ((uint4*)embb)[t] = o;
        B1[t] = 0.f;                       // B1 has V*16 floats: zero it here
    } else if (t < n_emb + 512 * 16) {
        int t2 = t - n_emb;
        int cp = t2 >> 4, g = t2 & 15;
        unsigned short u[8];
#pragma unroll
        for (int j = 0; j < 8; ++j) {
            int k = g * 8 + j;
            float w = (cp < 256) ? xiw[k * 256 + cp] : xiw[(128 + k) * 256 + (cp - 256)];
            u[j] = f2bf(w);
        }
        uint4 o;
        o.x = (unsigned)u[0] | ((unsigned)u[1] << 16);
        o.y = (unsigned)u[2] | ((unsigned)u[3] << 16);
        o.z = (unsigned)u[4] | ((unsigned)u[5] << 16);
        o.w = (unsigned)u[6] | ((unsigned)u[7] << 16);
        ((uint4*)WcT)[cp * 16 + (g ^ (cp & 7))] = o;
    } else if (t < n_emb + 512 * 16 + 256) {
        int t2 = t - n_emb - 512 * 16;
        int c = t2 >> 4, g = t2 & 15;
        unsigned short u[8];
#pragma unroll
        for (int j = 0; j < 8; ++j) u[j] = f2bf(rw[(g * 8 + j) * 16 + c]);
        uint4 o;
        o.x = (unsigned)u[0] | ((unsigned)u[1] << 16);
        o.y = (unsigned)u[2] | ((unsigned)u[3] << 16);
        o.z = (unsigned)u[4] | ((unsigned)u[5] << 16);
        o.w = (unsigned)u[6] | ((unsigned)u[7] << 16);
        ((uint4*)rouT)[c * 16 + (g ^ (c & 7))] = o;
    }
    if (t < E) atomicAdd(&cnt[Xe[t]], 1);   // fused histogram
}

// ---------------- two-level scan (3 small kernels, proven) ----------------
__global__ __launch_bounds__(256) void k_scan1(const int* __restrict__ cnt,
                                               int* __restrict__ rp,
                                               int* __restrict__ bsum, int V) {
    __shared__ int ls[256];
    int b = blockIdx.x, t = threadIdx.x;
    int i = b * 256 + t;
    int val = (i < V) ? cnt[i] : 0;
    ls[t] = val;
    __syncthreads();
    for (int off = 1; off < 256; off <<= 1) {
        int x = (t >= off) ? ls[t - off] : 0;
        __syncthreads();
        ls[t] += x;
        __syncthreads();
    }
    if (i < V) rp[i] = ls[t] - val;
    if (t == 255) bsum[b] = ls[255];
}

__global__ __launch_bounds__(256) void k_scan2(const int* __restrict__ bsum,
                                               int* __restrict__ boff,
                                               int* __restrict__ rp, int V, int NB) {
    __shared__ int ls[256];
    int t = threadIdx.x;
    int val = (t < NB) ? bsum[t] : 0;
    ls[t] = val;
    __syncthreads();
    for (int off = 1; off < 256; off <<= 1) {
        int x = (t >= off) ? ls[t - off] : 0;
        __syncthreads();
        ls[t] += x;
        __syncthreads();
    }
    if (t < NB) boff[t] = ls[t] - val;
    if (t == 255) rp[V] = ls[255];
}

__global__ void k_scan3(int* __restrict__ rp, const int* __restrict__ boff, int V) {
    int i = blockIdx.x * blockDim.x + threadIdx.x;
    if (i < V) rp[i] += boff[blockIdx.x];
}

// ---------------- permute (counting-sort placement) + fused pad fill ----------------
__global__ void k_permute(const int* __restrict__ Xn, const int* __restrict__ Xe,
                          const int* __restrict__ dg, const int* __restrict__ rp,
                          int* __restrict__ c2, int2* __restrict__ edata,
                          int* __restrict__ edst, int n, int Epad) {
    int e = blockIdx.x * blockDim.x + threadIdx.x;
    if (e < n) {
        int nb = Xe[e];
        int pos = rp[nb] + atomicAdd(&c2[nb], 1);
        edata[pos] = make_int2(Xn[e], __float_as_int(0.05625f / (float)dg[e]));
        edst[pos] = nb;
    } else if (e < Epad) {
        edata[e] = make_int2(0, 0);
        edst[e] = 0;
    }
}

// ---------------- U tables (e5m2) + bnode(f32) ----------------
__global__ __launch_bounds__(512) void k_U(
    const unsigned short* __restrict__ embb, const uint4* __restrict__ WcT,
    const uint4* __restrict__ rouT, const float* __restrict__ xib,
    const float* __restrict__ roub,
    unsigned* __restrict__ U8, unsigned* __restrict__ U28,
    float* __restrict__ bnode, int V) {
    __shared__ uint4 sB[2048];
    __shared__ uint4 sR[256];
    const int half = blockIdx.y;
    for (int i = threadIdx.x; i < 2048; i += 512) sB[i] = WcT[half * 2048 + i];
    if (half == 0 && threadIdx.x < 256) sR[threadIdx.x] = rouT[threadIdx.x];
    __syncthreads();

    const int wave = threadIdx.x >> 6, lane = threadIdx.x & 63;
    const int j = lane & 15, kg = lane >> 4;
    const int wbase = blockIdx.x * 512 + wave * 64;

    int nv[4];
#pragma unroll
    for (int g = 0; g < 4; ++g) nv[g] = min(wbase + g * 16 + j, V - 1);

    f32x4 acc[8][4] = {};
    f32x4 accb[4] = {};
#pragma unroll
    for (int kc = 0; kc < 4; ++kc) {
        bf16x8 bf[4];
#pragma unroll
        for (int g = 0; g < 4; ++g)
            bf[g] = *(const bf16x8*)(embb + (size_t)nv[g] * 128 + kc * 32 + kg * 8);
        int swz = (kc * 4 + kg) ^ (j & 7);
#pragma unroll
        for (int ct = 0; ct < 8; ++ct) {
            bf16x8 afr = ((const bf16x8*)sB)[(ct * 16 + j) * 16 + swz];
#pragma unroll
            for (int g = 0; g < 4; ++g)
                acc[ct][g] = __builtin_amdgcn_mfma_f32_16x16x32_bf16(afr, bf[g], acc[ct][g], 0, 0, 0);
        }
        if (half == 0) {
            bf16x8 rfr = ((const bf16x8*)sR)[j * 16 + swz];
#pragma unroll
            for (int g = 0; g < 4; ++g)
                accb[g] = __builtin_amdgcn_mfma_f32_16x16x32_bf16(rfr, bf[g], accb[g], 0, 0, 0);
        }
    }

#pragma unroll
    for (int ct = 0; ct < 8; ++ct) {
        int c0 = half * 128 + ct * 16 + kg * 4;     // 0..511
        float4 bias = (half < 2) ? ((const float4*)xib)[c0 >> 2]
                                 : make_float4(0.f, 0.f, 0.f, 0.f);
#pragma unroll
        for (int g = 0; g < 4; ++g) {
            int node = wbase + g * 16 + j;
            if (node < V) {
                const f32x4 a = acc[ct][g];
                float v0 = a[0] + bias.x, v1 = a[1] + bias.y;
                float v2 = a[2] + bias.z, v3 = a[3] + bias.w;
                unsigned pk = f2e5(v0) | (f2e5(v1) << 8) | (f2e5(v2) << 16) | (f2e5(v3) << 24);
                if (half < 2) U8[node * 64 + (c0 >> 2)] = pk;
                else          U28[node * 64 + ((c0 - 256) >> 2)] = pk;
            }
        }
    }
    if (half == 0) {
        float4 rb4 = ((const float4*)roub)[kg];
#pragma unroll
        for (int g = 0; g < 4; ++g) {
            int node = wbase + g * 16 + j;
            if (node < V) {
                float4 bo;
                bo.x = tanh_polyc(accb[g][0] + rb4.x);
                bo.y = tanh_polyc(accb[g][1] + rb4.y);
                bo.z = tanh_polyc(accb[g][2] + rb4.z);
                bo.w = tanh_polyc(accb[g][3] + rb4.w);
                *(float4*)(bnode + (size_t)node * 16 + kg * 4) = bo;
            }
        }
    }
}

// ---------------- edge-centric B1 (segment-sum of bnode[src]); B1 pre-zeroed ----------------
// 64 edges/wave; per-lane edge metadata held in registers, broadcast via shfl.
__global__ __launch_bounds__(256) void k_B1e(
    const float* __restrict__ bnode, const int2* __restrict__ edata,
    const int* __restrict__ edst, float* __restrict__ B1, int E, int Epad) {
    int wid = (blockIdx.x * 256 + threadIdx.x) >> 6;
    int wbase = wid * 64;
    if (wbase >= Epad) return;
    int lane = threadIdx.x & 63;
    int g = lane >> 4, s = lane & 15, lbase = g * 16;
    int sbase = wbase + lbase;

    int em = wbase + lane;
    int my_u = edata[em].x;
    int d_own = edst[em];
    int d_nxt = edst[min(em + 1, Epad - 1)];
    unsigned long long flags = __ballot(d_own != d_nxt);

    int cur = __shfl(d_own, lbase, 64);
    float acc = 0.f;
#pragma unroll 4
    for (int j = 0; j < 16; ++j) {
        int p = sbase + j;
        int u = __shfl(my_u, lbase + j, 64);
        float v = bnode[(size_t)u * 16 + s];
        acc += (p < E) ? v : 0.f;
        bool flush = ((flags >> (lbase + j)) & 1ull) || (j == 15);
        if (flush) {
            atomicAdd(&B1[(size_t)cur * 16 + s], acc);
            acc = 0.f;
            if (j < 15) cur = __shfl(d_nxt, lbase + j, 64);
        }
    }
}

// ---------------- prep: Hf = f16x2(st); optionally copy st into two state buffers ----------------
__global__ void k_prep(const float* __restrict__ st, unsigned* __restrict__ Hf,
                       float* __restrict__ cp1, float* __restrict__ cp2, int n2) {
    int i = blockIdx.x * blockDim.x + threadIdx.x;
    if (i >= n2) return;
    float2 f = ((const float2*)st)[i];
    half2_t h = {(_Float16)f.x, (_Float16)f.y};
    Hf[i] = h2u(h);
    if (cp1 != nullptr) {
        ((float2*)cp1)[i] = f;
        ((float2*)cp2)[i] = f;
    }
}

// ---------------- edge-centric prop (e5m2 U-tables, packed-f16 math, dot2 accumulate) ----------------
// sn pre-initialized to B1. 64 edges/wave; edge metadata register-resident, shfl-broadcast.
__global__ __launch_bounds__(256) void k_prop_e(
    const unsigned* __restrict__ U8, const unsigned* __restrict__ U28,
    const int2* __restrict__ edata, const int* __restrict__ edst,
    const unsigned* __restrict__ Hf,
    float* __restrict__ sn, int Epad) {
    int wid = (blockIdx.x * 256 + threadIdx.x) >> 6;
    int wbase = wid * 64;
    if (wbase >= Epad) return;
    int lane = threadIdx.x & 63;
    int g = lane >> 4, s = lane & 15, lbase = g * 16;

    int em = wbase + lane;
    int2 myed = edata[em];
    int d_own = edst[em];
    int d_nxt = edst[min(em + 1, Epad - 1)];
    unsigned long long flags = __ballot(d_own != d_nxt);

    int cur = __shfl(d_own, lbase, 64);
    half2_t u2h[8];
    {
        uint4 r = ((const uint4*)U28)[cur * 16 + s];
        unsigned wr[4] = {r.x, r.y, r.z, r.w};
#pragma unroll
        for (int q = 0; q < 4; ++q) {
            u2h[2 * q]     = u2h2(__builtin_amdgcn_perm(wr[q], 0u, 0x05000400u));
            u2h[2 * q + 1] = u2h2(__builtin_amdgcn_perm(wr[q], 0u, 0x07000600u));
        }
    }

    float acc = 0.f;
#pragma unroll 4
    for (int j = 0; j < 16; ++j) {
        int u = __shfl(myed.x, lbase + j, 64);
        float sc = __int_as_float(__shfl(myed.y, lbase + j, 64));
        uint4 q1 = ((const uint4*)U8)[u * 16 + s];
        unsigned h2 = Hf[u * 8 + (s & 7)];
        unsigned wq[4] = {q1.x, q1.y, q1.z, q1.w};
        float sum = 0.f;
#pragma unroll
        for (int q = 0; q < 4; ++q) {
            half2_t x0 = u2h2(__builtin_amdgcn_perm(wq[q], 0u, 0x05000400u)) + u2h[2 * q];
            half2_t x1 = u2h2(__builtin_amdgcn_perm(wq[q], 0u, 0x07000600u)) + u2h[2 * q + 1];
            half2_t r0 = tanh_pk(x0);
            half2_t r1 = tanh_pk(x1);
            unsigned hm0 = __shfl(h2, lbase + 2 * q, 64);
            unsigned hm1 = __shfl(h2, lbase + 2 * q + 1, 64);
            sum = __builtin_amdgcn_fdot2(r0, u2h2(hm0), sum, false);
            sum = __builtin_amdgcn_fdot2(r1, u2h2(hm1), sum, false);
        }
        acc = fmaf(sc, sum, acc);
        bool flush = ((flags >> (lbase + j)) & 1ull) || (j == 15);
        if (flush) {
            atomicAdd(&sn[(size_t)cur * 16 + s], acc);
            acc = 0.f;
            if (j < 15) {
                cur = __shfl(d_nxt, lbase + j, 64);
                uint4 r = ((const uint4*)U28)[cur * 16 + s];
                unsigned wr[4] = {r.x, r.y, r.z, r.w};
#pragma unroll
                for (int q = 0; q < 4; ++q) {
                    u2h[2 * q]     = u2h2(__builtin_amdgcn_perm(wr[q], 0u, 0x05000400u));
                    u2h[2 * q + 1] = u2h2(__builtin_amdgcn_perm(wr[q], 0u, 0x07000600u));
                }
            }
        }
    }
}

// ---------------- final: softmax([emb, states] @ lin_w + lin_b) ----------------
__global__ void k_final(const unsigned short* __restrict__ embb, const float* __restrict__ st,
                        const float* __restrict__ lw, const float* __restrict__ lb,
                        float* __restrict__ out, int nv) {
    __shared__ float sw[435];
    for (int i = threadIdx.x; i < 435; i += 256) sw[i] = (i < 432) ? lw[i] : lb[i - 432];
    __syncthreads();
    int t = blockIdx.x * blockDim.x + threadIdx.x;
    int v = t >> 4, j = t & 15;
    if (v >= nv) return;
    const uint4 q = *(const uint4*)(embb + (size_t)v * 128 + j * 8);
    unsigned uu[4] = {q.x, q.y, q.z, q.w};
    float a0 = 0.f, a1 = 0.f, a2 = 0.f;
#pragma unroll
    for (int m = 0; m < 4; ++m) {
        int i = j * 8 + 2 * m;
        float x0 = bflo(uu[m]), x1 = bfhi(uu[m]);
        a0 += x0 * sw[i * 3] + x1 * sw[(i + 1) * 3];
        a1 += x0 * sw[i * 3 + 1] + x1 * sw[(i + 1) * 3 + 1];
        a2 += x0 * sw[i * 3 + 2] + x1 * sw[(i + 1) * 3 + 2];
    }
    float xs = st[(size_t)v * 16 + j];
    a0 += xs * sw[(128 + j) * 3]; a1 += xs * sw[(128 + j) * 3 + 1]; a2 += xs * sw[(128 + j) * 3 + 2];
#pragma unroll
    for (int m = 1; m < 16; m <<= 1) {
        a0 += __shfl_xor(a0, m, 64);
        a1 += __shfl_xor(a1, m, 64);
        a2 += __shfl_xor(a2, m, 64);
    }
    if (j == 0) {
        a0 += sw[432]; a1 += sw[433]; a2 += sw[434];
        float mx = fmaxf(a0, fmaxf(a1, a2));
        float e0 = __expf(a0 - mx), e1 = __expf(a1 - mx), e2 = __expf(a2 - mx);
        float inv = 1.f / (e0 + e1 + e2);
        out[(size_t)v * 3 + 0] = e0 * inv;
        out[(size_t)v * 3 + 1] = e1 * inv;
        out[(size_t)v * 3 + 2] = e2 * inv;
    }
}

extern "C" void kernel_launch(void* const* d_in, const int* in_sizes, int n_in,
                              void* d_out, int out_size, void* d_ws, size_t ws_size,
                              hipStream_t stream) {
    const int*   Xn  = (const int*)d_in[0];
    const int*   Xe  = (const int*)d_in[1];
    const int*   dg  = (const int*)d_in[2];
    const float* emb = (const float*)d_in[3];
    const float* xiw = (const float*)d_in[4];
    const float* xib = (const float*)d_in[5];
    const float* rw  = (const float*)d_in[6];
    const float* rb  = (const float*)d_in[7];
    const float* lw  = (const float*)d_in[8];
    const float* lb  = (const float*)d_in[9];
    float* out = (float*)d_out;
    const int E = in_sizes[0];
    const int V = in_sizes[3] / LN_F;
    const int NB = (V + 255) / 256;            // <= 256 required (V <= 65536)
    const int Epad = (E + 63) & ~63;

    char* p = (char*)d_ws;
    auto carve = [&](size_t bytes) {
        char* q = p; p += (bytes + 255) & ~(size_t)255; return q;
    };
    int*   cnt   = (int*)carve((size_t)V * 4);
    int*   c2    = (int*)carve((size_t)V * 4);
    size_t zero_bytes = (size_t)(p - (char*)cnt);
    float* B1    = (float*)carve((size_t)V * 16 * 4);
    unsigned short* embb = (unsigned short*)carve((size_t)V * 128 * 2);
    unsigned* U8    = (unsigned*)carve((size_t)V * 256);
    unsigned* U28   = (unsigned*)carve((size_t)V * 256);
    uint4* WcT   = (uint4*)carve(512 * 16 * 16);
    uint4* rouT  = (uint4*)carve(4096);
    float* bnode = (float*)carve((size_t)V * 16 * 4);
    float* stB   = (float*)carve((size_t)V * 16 * 4);
    float* stA   = (float*)carve((size_t)V * 16 * 4);
    unsigned* Hf = (unsigned*)carve((size_t)V * 16 * 2);
    int*   rp    = (int*)carve((size_t)(V + 1) * 4);
    int*   bsum  = (int*)carve(256 * 4);
    int*   boff  = (int*)carve(256 * 4);
    int2*  edata = (int2*)carve((size_t)Epad * 8);
    int*   edst  = (int*)carve((size_t)Epad * 4);

    // 1: zero cnt/c2
    hipMemsetAsync(cnt, 0, zero_bytes, stream);

    // 2: conversions + histogram + B1 zero
    {
        int nconv = V * 16 + 512 * 16 + 256;
        int ntot = nconv > E ? nconv : E;
        k_conv<<<(ntot + 255) / 256, 256, 0, stream>>>(
            emb, xiw, rw, Xe, embb, (unsigned short*)WcT, (unsigned short*)rouT,
            cnt, B1, V, E);
    }

    // 3-5: two-level scan
    k_scan1<<<NB, 256, 0, stream>>>(cnt, rp, bsum, V);
    k_scan2<<<1, 256, 0, stream>>>(bsum, boff, rp, V, NB);
    k_scan3<<<NB, 256, 0, stream>>>(rp, boff, V);

    // 6: permute + pad fill
    {
        int ng = (Epad > E ? Epad : E);
        k_permute<<<(ng + 255) / 256, 256, 0, stream>>>(Xn, Xe, dg, rp, c2, edata, edst, E, Epad);
    }

    // 7: U tables + bnode
    {
        dim3 g((V + 511) / 512, 4);
        k_U<<<g, 512, 0, stream>>>(embb, WcT, rouT, xib, rb, U8, U28, bnode, V);
    }

    const int n2 = V * 8;
    const int pblocks = (Epad / 64 + 3) / 4;

    // 8: states1 = B1 += segment-sum of bnode[src]
    k_B1e<<<pblocks, 256, 0, stream>>>(bnode, edata, edst, B1, E, Epad);

    // 9-10: step 2
    k_prep<<<(n2 + 255) / 256, 256, 0, stream>>>(B1, Hf, stB, stA, n2);
    k_prop_e<<<pblocks, 256, 0, stream>>>(U8, U28, edata, edst, Hf, stB, Epad);

    // 11-12: step 3
    k_prep<<<(n2 + 255) / 256, 256, 0, stream>>>(stB, Hf, nullptr, nullptr, n2);
    k_prop_e<<<pblocks, 256, 0, stream>>>(U8, U28, edata, edst, Hf, stA, Epad);

    // 13: output
    k_final<<<((size_t)V * 16 + 255) / 256, 256, 0, stream>>>(embb, stA, lw, lb, out, V);
}

// Round 11
// 178.595 us; speedup vs baseline: 7.6152x; 1.0339x over previous
//
#include <hip/hip_runtime.h>
#include <hip/hip_bf16.h>
#include <hip/hip_fp16.h>

#define LN_F 128

typedef __attribute__((ext_vector_type(8))) __bf16 bf16x8;
typedef __attribute__((ext_vector_type(4))) float f32x4;
typedef __attribute__((ext_vector_type(2))) _Float16 half2_t;

__device__ __forceinline__ unsigned short f2bf(float f) {
    unsigned u = __float_as_uint(f);
    u = u + 0x7FFFu + ((u >> 16) & 1u);   // RNE
    return (unsigned short)(u >> 16);
}
// deg-7 odd Taylor (f32, cold paths)
__device__ __forceinline__ float tanh_polyc(float x) {
    x = fminf(1.2f, fmaxf(-1.2f, x));
    float t = x * x;
    float p = fmaf(t, -0.05396825397f, 0.13333333333f);
    p = fmaf(t, p, -0.33333333333f);
    p = fmaf(t, p, 1.0f);
    return x * p;
}
__device__ __forceinline__ float bflo(unsigned u) { return __uint_as_float(u << 16); }
__device__ __forceinline__ float bfhi(unsigned u) { return __uint_as_float(u & 0xffff0000u); }

// f32 -> e5m2 byte (e5m2 == top byte of f16; double-RNE)
__device__ __forceinline__ unsigned f2e5(float x) {
    unsigned short u = __half_as_ushort(__float2half(x));
    u = (unsigned short)(u + 0x7F + ((u >> 8) & 1));
    return (unsigned)(u >> 8) & 0xFFu;
}
__device__ __forceinline__ half2_t u2h2(unsigned w) {
    union { unsigned u; half2_t h; } c; c.u = w; return c.h;
}
__device__ __forceinline__ unsigned h2u(half2_t h) {
    union { half2_t h; unsigned u; } c; c.h = h; return c.u;
}
// packed deg-5 odd Taylor tanh on half2
__device__ __forceinline__ half2_t tanh_pk(half2_t x) {
    const half2_t c2 = {(_Float16)(2.0f / 15.0f), (_Float16)(2.0f / 15.0f)};
    const half2_t c1 = {(_Float16)(-1.0f / 3.0f), (_Float16)(-1.0f / 3.0f)};
    const half2_t one = {(_Float16)1.0f, (_Float16)1.0f};
    half2_t t = x * x;
    half2_t p = t * c2 + c1;
    p = t * p + one;
    return x * p;
}

// ---------------- conversions (emb/Wc/rou) + fused histogram + B1 zero ----------------
__global__ void k_conv(const float* __restrict__ emb, const float* __restrict__ xiw,
                       const float* __restrict__ rw, const int* __restrict__ Xe,
                       unsigned short* __restrict__ embb, unsigned short* __restrict__ WcT,
                       unsigned short* __restrict__ rouT, int* __restrict__ cnt,
                       float* __restrict__ B1, int V, int E) {
    int t = blockIdx.x * blockDim.x + threadIdx.x;
    int n_emb = V * 16;
    if (t < n_emb) {
        const float4* s = (const float4*)emb;
        float4 a = s[t * 2], b = s[t * 2 + 1];
        uint4 o;
        o.x = (unsigned)f2bf(a.x) | ((unsigned)f2bf(a.y) << 16);
        o.y = (unsigned)f2bf(a.z) | ((unsigned)f2bf(a.w) << 16);
        o.z = (unsigned)f2bf(b.x) | ((unsigned)f2bf(b.y) << 16);
        o.w = (unsigned)f2bf(b.z) | ((unsigned)f2bf(b.w) << 16);
        ((uint4*)embb)[t] = o;
        B1[t] = 0.f;                       // B1 has V*16 floats: zero it here
    } else if (t < n_emb + 512 * 16) {
        int t2 = t - n_emb;
        int cp = t2 >> 4, g = t2 & 15;
        unsigned short u[8];
#pragma unroll
        for (int j = 0; j < 8; ++j) {
            int k = g * 8 + j;
            float w = (cp < 256) ? xiw[k * 256 + cp] : xiw[(128 + k) * 256 + (cp - 256)];
            u[j] = f2bf(w);
        }
        uint4 o;
        o.x = (unsigned)u[0] | ((unsigned)u[1] << 16);
        o.y = (unsigned)u[2] | ((unsigned)u[3] << 16);
        o.z = (unsigned)u[4] | ((unsigned)u[5] << 16);
        o.w = (unsigned)u[6] | ((unsigned)u[7] << 16);
        ((uint4*)WcT)[cp * 16 + (g ^ (cp & 7))] = o;
    } else if (t < n_emb + 512 * 16 + 256) {
        int t2 = t - n_emb - 512 * 16;
        int c = t2 >> 4, g = t2 & 15;
        unsigned short u[8];
#pragma unroll
        for (int j = 0; j < 8; ++j) u[j] = f2bf(rw[(g * 8 + j) * 16 + c]);
        uint4 o;
        o.x = (unsigned)u[0] | ((unsigned)u[1] << 16);
        o.y = (unsigned)u[2] | ((unsigned)u[3] << 16);
        o.z = (unsigned)u[4] | ((unsigned)u[5] << 16);
        o.w = (unsigned)u[6] | ((unsigned)u[7] << 16);
        ((uint4*)rouT)[c * 16 + (g ^ (c & 7))] = o;
    }
    if (t < E) atomicAdd(&cnt[Xe[t]], 1);   // fused histogram
}

// ---------------- two-level scan (block-local scan + block sums) ----------------
__global__ __launch_bounds__(256) void k_scan1(const int* __restrict__ cnt,
                                               int* __restrict__ rp,
                                               int* __restrict__ bsum, int V) {
    __shared__ int ls[256];
    int b = blockIdx.x, t = threadIdx.x;
    int i = b * 256 + t;
    int val = (i < V) ? cnt[i] : 0;
    ls[t] = val;
    __syncthreads();
    for (int off = 1; off < 256; off <<= 1) {
        int x = (t >= off) ? ls[t - off] : 0;
        __syncthreads();
        ls[t] += x;
        __syncthreads();
    }
    if (i < V) rp[i] = ls[t] - val;   // block-local exclusive
    if (t == 255) bsum[b] = ls[255];
}

__global__ __launch_bounds__(256) void k_scan2(const int* __restrict__ bsum,
                                               int* __restrict__ boff, int NB) {
    __shared__ int ls[256];
    int t = threadIdx.x;
    int val = (t < NB) ? bsum[t] : 0;
    ls[t] = val;
    __syncthreads();
    for (int off = 1; off < 256; off <<= 1) {
        int x = (t >= off) ? ls[t - off] : 0;
        __syncthreads();
        ls[t] += x;
        __syncthreads();
    }
    if (t < NB) boff[t] = ls[t] - val;
}

// ---------------- permute: counting-sort placement, packed 8B record, fused boff + pad ----------------
// record: x = src | (dst << 16)  (V < 65536), y = f32 scale bits
__global__ void k_permute(const int* __restrict__ Xn, const int* __restrict__ Xe,
                          const int* __restrict__ dg, const int* __restrict__ rp,
                          const int* __restrict__ boff, int* __restrict__ c2,
                          uint2* __restrict__ erec, int n, int Epad) {
    int e = blockIdx.x * blockDim.x + threadIdx.x;
    if (e < n) {
        int nb = Xe[e];
        int pos = rp[nb] + boff[nb >> 8] + atomicAdd(&c2[nb], 1);
        uint2 r;
        r.x = (unsigned)Xn[e] | ((unsigned)nb << 16);
        r.y = (unsigned)__float_as_int(0.05625f / (float)dg[e]);
        erec[pos] = r;
    } else if (e < Epad) {
        erec[e] = make_uint2(0u, 0u);
    }
}

// ---------------- U tables (e5m2) + bnode(f32) ----------------
__global__ __launch_bounds__(512) void k_U(
    const unsigned short* __restrict__ embb, const uint4* __restrict__ WcT,
    const uint4* __restrict__ rouT, const float* __restrict__ xib,
    const float* __restrict__ roub,
    unsigned* __restrict__ U8, unsigned* __restrict__ U28,
    float* __restrict__ bnode, int V) {
    __shared__ uint4 sB[2048];
    __shared__ uint4 sR[256];
    const int half = blockIdx.y;
    for (int i = threadIdx.x; i < 2048; i += 512) sB[i] = WcT[half * 2048 + i];
    if (half == 0 && threadIdx.x < 256) sR[threadIdx.x] = rouT[threadIdx.x];
    __syncthreads();

    const int wave = threadIdx.x >> 6, lane = threadIdx.x & 63;
    const int j = lane & 15, kg = lane >> 4;
    const int wbase = blockIdx.x * 512 + wave * 64;

    int nv[4];
#pragma unroll
    for (int g = 0; g < 4; ++g) nv[g] = min(wbase + g * 16 + j, V - 1);

    f32x4 acc[8][4] = {};
    f32x4 accb[4] = {};
#pragma unroll
    for (int kc = 0; kc < 4; ++kc) {
        bf16x8 bf[4];
#pragma unroll
        for (int g = 0; g < 4; ++g)
            bf[g] = *(const bf16x8*)(embb + (size_t)nv[g] * 128 + kc * 32 + kg * 8);
        int swz = (kc * 4 + kg) ^ (j & 7);
#pragma unroll
        for (int ct = 0; ct < 8; ++ct) {
            bf16x8 afr = ((const bf16x8*)sB)[(ct * 16 + j) * 16 + swz];
#pragma unroll
            for (int g = 0; g < 4; ++g)
                acc[ct][g] = __builtin_amdgcn_mfma_f32_16x16x32_bf16(afr, bf[g], acc[ct][g], 0, 0, 0);
        }
        if (half == 0) {
            bf16x8 rfr = ((const bf16x8*)sR)[j * 16 + swz];
#pragma unroll
            for (int g = 0; g < 4; ++g)
                accb[g] = __builtin_amdgcn_mfma_f32_16x16x32_bf16(rfr, bf[g], accb[g], 0, 0, 0);
        }
    }

#pragma unroll
    for (int ct = 0; ct < 8; ++ct) {
        int c0 = half * 128 + ct * 16 + kg * 4;     // 0..511
        float4 bias = (half < 2) ? ((const float4*)xib)[c0 >> 2]
                                 : make_float4(0.f, 0.f, 0.f, 0.f);
#pragma unroll
        for (int g = 0; g < 4; ++g) {
            int node = wbase + g * 16 + j;
            if (node < V) {
                const f32x4 a = acc[ct][g];
                float v0 = a[0] + bias.x, v1 = a[1] + bias.y;
                float v2 = a[2] + bias.z, v3 = a[3] + bias.w;
                unsigned pk = f2e5(v0) | (f2e5(v1) << 8) | (f2e5(v2) << 16) | (f2e5(v3) << 24);
                if (half < 2) U8[node * 64 + (c0 >> 2)] = pk;
                else          U28[node * 64 + ((c0 - 256) >> 2)] = pk;
            }
        }
    }
    if (half == 0) {
        float4 rb4 = ((const float4*)roub)[kg];
#pragma unroll
        for (int g = 0; g < 4; ++g) {
            int node = wbase + g * 16 + j;
            if (node < V) {
                float4 bo;
                bo.x = tanh_polyc(accb[g][0] + rb4.x);
                bo.y = tanh_polyc(accb[g][1] + rb4.y);
                bo.z = tanh_polyc(accb[g][2] + rb4.z);
                bo.w = tanh_polyc(accb[g][3] + rb4.w);
                *(float4*)(bnode + (size_t)node * 16 + kg * 4) = bo;
            }
        }
    }
}

// ---------------- edge-centric B1 (segment-sum of bnode[src]); B1 pre-zeroed ----------------
// 64 edges/wave; per-lane edge metadata register-resident, shfl-broadcast.
__global__ __launch_bounds__(256) void k_B1e(
    const float* __restrict__ bnode, const uint2* __restrict__ erec,
    float* __restrict__ B1, int E, int Epad) {
    int wid = (blockIdx.x * 256 + threadIdx.x) >> 6;
    int wbase = wid * 64;
    if (wbase >= Epad) return;
    int lane = threadIdx.x & 63;
    int g = lane >> 4, s = lane & 15, lbase = g * 16;
    int sbase = wbase + lbase;

    int em = wbase + lane;
    unsigned rx = erec[em].x;
    int my_u = (int)(rx & 0xFFFFu);
    int d_own = (int)(rx >> 16);
    int d_nxt = (int)(((const unsigned*)erec)[2 * min(em + 1, Epad - 1)] >> 16);
    unsigned long long flags = __ballot(d_own != d_nxt);

    int cur = __shfl(d_own, lbase, 64);
    float acc = 0.f;
#pragma unroll 4
    for (int j = 0; j < 16; ++j) {
        int p = sbase + j;
        int u = __shfl(my_u, lbase + j, 64);
        float v = bnode[(size_t)u * 16 + s];
        acc += (p < E) ? v : 0.f;
        bool flush = ((flags >> (lbase + j)) & 1ull) || (j == 15);
        if (flush) {
            atomicAdd(&B1[(size_t)cur * 16 + s], acc);
            acc = 0.f;
            if (j < 15) cur = __shfl(d_nxt, lbase + j, 64);
        }
    }
}

// ---------------- prep: Hf = f16x2(st); optionally copy st into two state buffers ----------------
__global__ void k_prep(const float* __restrict__ st, unsigned* __restrict__ Hf,
                       float* __restrict__ cp1, float* __restrict__ cp2, int n2) {
    int i = blockIdx.x * blockDim.x + threadIdx.x;
    if (i >= n2) return;
    float2 f = ((const float2*)st)[i];
    half2_t h = {(_Float16)f.x, (_Float16)f.y};
    Hf[i] = h2u(h);
    if (cp1 != nullptr) {
        ((float2*)cp1)[i] = f;
        ((float2*)cp2)[i] = f;
    }
}

// ---------------- edge-centric prop (e5m2 U-tables, packed-f16 math, dot2 accumulate) ----------------
// sn pre-initialized to B1. 64 edges/wave; packed record register-resident, shfl-broadcast.
__global__ __launch_bounds__(256) void k_prop_e(
    const unsigned* __restrict__ U8, const unsigned* __restrict__ U28,
    const uint2* __restrict__ erec, const unsigned* __restrict__ Hf,
    float* __restrict__ sn, int Epad) {
    int wid = (blockIdx.x * 256 + threadIdx.x) >> 6;
    int wbase = wid * 64;
    if (wbase >= Epad) return;
    int lane = threadIdx.x & 63;
    int g = lane >> 4, s = lane & 15, lbase = g * 16;

    int em = wbase + lane;
    uint2 myr = erec[em];
    int my_u = (int)(myr.x & 0xFFFFu);
    int d_own = (int)(myr.x >> 16);
    int d_nxt = (int)(((const unsigned*)erec)[2 * min(em + 1, Epad - 1)] >> 16);
    unsigned long long flags = __ballot(d_own != d_nxt);

    int cur = __shfl(d_own, lbase, 64);
    half2_t u2h[8];
    {
        uint4 r = ((const uint4*)U28)[cur * 16 + s];
        unsigned wr[4] = {r.x, r.y, r.z, r.w};
#pragma unroll
        for (int q = 0; q < 4; ++q) {
            u2h[2 * q]     = u2h2(__builtin_amdgcn_perm(wr[q], 0u, 0x05000400u));
            u2h[2 * q + 1] = u2h2(__builtin_amdgcn_perm(wr[q], 0u, 0x07000600u));
        }
    }

    float acc = 0.f;
#pragma unroll 4
    for (int j = 0; j < 16; ++j) {
        int u = __shfl(my_u, lbase + j, 64);
        float sc = __int_as_float(__shfl((int)myr.y, lbase + j, 64));
        uint4 q1 = ((const uint4*)U8)[u * 16 + s];
        unsigned h2 = Hf[u * 8 + (s & 7)];
        unsigned wq[4] = {q1.x, q1.y, q1.z, q1.w};
        float sum = 0.f;
#pragma unroll
        for (int q = 0; q < 4; ++q) {
            half2_t x0 = u2h2(__builtin_amdgcn_perm(wq[q], 0u, 0x05000400u)) + u2h[2 * q];
            half2_t x1 = u2h2(__builtin_amdgcn_perm(wq[q], 0u, 0x07000600u)) + u2h[2 * q + 1];
            half2_t r0 = tanh_pk(x0);
            half2_t r1 = tanh_pk(x1);
            unsigned hm0 = __shfl(h2, lbase + 2 * q, 64);
            unsigned hm1 = __shfl(h2, lbase + 2 * q + 1, 64);
            sum = __builtin_amdgcn_fdot2(r0, u2h2(hm0), sum, false);
            sum = __builtin_amdgcn_fdot2(r1, u2h2(hm1), sum, false);
        }
        acc = fmaf(sc, sum, acc);
        bool flush = ((flags >> (lbase + j)) & 1ull) || (j == 15);
        if (flush) {
            atomicAdd(&sn[(size_t)cur * 16 + s], acc);
            acc = 0.f;
            if (j < 15) {
                cur = __shfl(d_nxt, lbase + j, 64);
                uint4 r = ((const uint4*)U28)[cur * 16 + s];
                unsigned wr[4] = {r.x, r.y, r.z, r.w};
#pragma unroll
                for (int q = 0; q < 4; ++q) {
                    u2h[2 * q]     = u2h2(__builtin_amdgcn_perm(wr[q], 0u, 0x05000400u));
                    u2h[2 * q + 1] = u2h2(__builtin_amdgcn_perm(wr[q], 0u, 0x07000600u));
                }
            }
        }
    }
}

// ---------------- final: softmax([emb, states] @ lin_w + lin_b) ----------------
__global__ void k_final(const unsigned short* __restrict__ embb, const float* __restrict__ st,
                        const float* __restrict__ lw, const float* __restrict__ lb,
                        float* __restrict__ out, int nv) {
    __shared__ float sw[435];
    for (int i = threadIdx.x; i < 435; i += 256) sw[i] = (i < 432) ? lw[i] : lb[i - 432];
    __syncthreads();
    int t = blockIdx.x * blockDim.x + threadIdx.x;
    int v = t >> 4, j = t & 15;
    if (v >= nv) return;
    const uint4 q = *(const uint4*)(embb + (size_t)v * 128 + j * 8);
    unsigned uu[4] = {q.x, q.y, q.z, q.w};
    float a0 = 0.f, a1 = 0.f, a2 = 0.f;
#pragma unroll
    for (int m = 0; m < 4; ++m) {
        int i = j * 8 + 2 * m;
        float x0 = bflo(uu[m]), x1 = bfhi(uu[m]);
        a0 += x0 * sw[i * 3] + x1 * sw[(i + 1) * 3];
        a1 += x0 * sw[i * 3 + 1] + x1 * sw[(i + 1) * 3 + 1];
        a2 += x0 * sw[i * 3 + 2] + x1 * sw[(i + 1) * 3 + 2];
    }
    float xs = st[(size_t)v * 16 + j];
    a0 += xs * sw[(128 + j) * 3]; a1 += xs * sw[(128 + j) * 3 + 1]; a2 += xs * sw[(128 + j) * 3 + 2];
#pragma unroll
    for (int m = 1; m < 16; m <<= 1) {
        a0 += __shfl_xor(a0, m, 64);
        a1 += __shfl_xor(a1, m, 64);
        a2 += __shfl_xor(a2, m, 64);
    }
    if (j == 0) {
        a0 += sw[432]; a1 += sw[433]; a2 += sw[434];
        float mx = fmaxf(a0, fmaxf(a1, a2));
        float e0 = __expf(a0 - mx), e1 = __expf(a1 - mx), e2 = __expf(a2 - mx);
        float inv = 1.f / (e0 + e1 + e2);
        out[(size_t)v * 3 + 0] = e0 * inv;
        out[(size_t)v * 3 + 1] = e1 * inv;
        out[(size_t)v * 3 + 2] = e2 * inv;
    }
}

extern "C" void kernel_launch(void* const* d_in, const int* in_sizes, int n_in,
                              void* d_out, int out_size, void* d_ws, size_t ws_size,
                              hipStream_t stream) {
    const int*   Xn  = (const int*)d_in[0];
    const int*   Xe  = (const int*)d_in[1];
    const int*   dg  = (const int*)d_in[2];
    const float* emb = (const float*)d_in[3];
    const float* xiw = (const float*)d_in[4];
    const float* xib = (const float*)d_in[5];
    const float* rw  = (const float*)d_in[6];
    const float* rb  = (const float*)d_in[7];
    const float* lw  = (const float*)d_in[8];
    const float* lb  = (const float*)d_in[9];
    float* out = (float*)d_out;
    const int E = in_sizes[0];
    const int V = in_sizes[3] / LN_F;          // note: packed record requires V < 65536
    const int NB = (V + 255) / 256;            // <= 256 required (V <= 65536)
    const int Epad = (E + 63) & ~63;

    char* p = (char*)d_ws;
    auto carve = [&](size_t bytes) {
        char* q = p; p += (bytes + 255) & ~(size_t)255; return q;
    };
    int*   cnt   = (int*)carve((size_t)V * 4);
    int*   c2    = (int*)carve((size_t)V * 4);
    size_t zero_bytes = (size_t)(p - (char*)cnt);
    float* B1    = (float*)carve((size_t)V * 16 * 4);
    unsigned short* embb = (unsigned short*)carve((size_t)V * 128 * 2);
    unsigned* U8    = (unsigned*)carve((size_t)V * 256);
    unsigned* U28   = (unsigned*)carve((size_t)V * 256);
    uint4* WcT   = (uint4*)carve(512 * 16 * 16);
    uint4* rouT  = (uint4*)carve(4096);
    float* bnode = (float*)carve((size_t)V * 16 * 4);
    float* stB   = (float*)carve((size_t)V * 16 * 4);
    float* stA   = (float*)carve((size_t)V * 16 * 4);
    unsigned* Hf = (unsigned*)carve((size_t)V * 16 * 2);
    int*   rp    = (int*)carve((size_t)(V + 1) * 4);
    int*   bsum  = (int*)carve(256 * 4);
    int*   boff  = (int*)carve(256 * 4);
    uint2* erec  = (uint2*)carve((size_t)Epad * 8);

    // 1: zero cnt/c2
    hipMemsetAsync(cnt, 0, zero_bytes, stream);

    // 2: conversions + histogram + B1 zero
    {
        int nconv = V * 16 + 512 * 16 + 256;
        int ntot = nconv > E ? nconv : E;
        k_conv<<<(ntot + 255) / 256, 256, 0, stream>>>(
            emb, xiw, rw, Xe, embb, (unsigned short*)WcT, (unsigned short*)rouT,
            cnt, B1, V, E);
    }

    // 3-4: two-level scan (block-local rp + block offsets)
    k_scan1<<<NB, 256, 0, stream>>>(cnt, rp, bsum, V);
    k_scan2<<<1, 256, 0, stream>>>(bsum, boff, NB);

    // 5: permute (packed 8B record, fused boff add + pad fill)
    {
        int ng = (Epad > E ? Epad : E);
        k_permute<<<(ng + 255) / 256, 256, 0, stream>>>(Xn, Xe, dg, rp, boff, c2, erec, E, Epad);
    }

    // 6: U tables + bnode
    {
        dim3 g((V + 511) / 512, 4);
        k_U<<<g, 512, 0, stream>>>(embb, WcT, rouT, xib, rb, U8, U28, bnode, V);
    }

    const int n2 = V * 8;
    const int pblocks = (Epad / 64 + 3) / 4;

    // 7: states1 = B1 += segment-sum of bnode[src]
    k_B1e<<<pblocks, 256, 0, stream>>>(bnode, erec, B1, E, Epad);

    // 8-9: step 2
    k_prep<<<(n2 + 255) / 256, 256, 0, stream>>>(B1, Hf, stB, stA, n2);
    k_prop_e<<<pblocks, 256, 0, stream>>>(U8, U28, erec, Hf, stB, Epad);

    // 10-11: step 3
    k_prep<<<(n2 + 255) / 256, 256, 0, stream>>>(stB, Hf, nullptr, nullptr, n2);
    k_prop_e<<<pblocks, 256, 0, stream>>>(U8, U28, erec, Hf, stA, Epad);

    // 12: output
    k_final<<<((size_t)V * 16 + 255) / 256, 256, 0, stream>>>(embb, stA, lw, lb, out, V);
}